// Round 9
// baseline (91.708 us; speedup 1.0000x reference)
//
#include <hip/hip_runtime.h>
#include <math.h>

// Problem constants (fixed by reference: inp (4,16,32,32) f32, weight (64,144) f32)
constexpr int F_IN   = 144;   // 16 ch * 9 taps
constexpr int F_OUT  = 64;
constexpr int H_IMG  = 32;
constexpr int W_IMG  = 32;
constexpr int NPIX   = 4 * H_IMG * W_IMG;  // 4096
constexpr int PPB    = 8;                  // pixels per block (1 wave each)
constexpr int NTHR   = PPB * 64;           // 512
#define MAX_SPIKE 100.0f

__device__ __forceinline__ unsigned rl_u32(unsigned v, int j) {
    return (unsigned)__builtin_amdgcn_readlane((int)v, j);
}

// ---------------------------------------------------------------------------
// FUSED kernel (single dispatch): quant + sort + scan per block.
//
// Quant (bit-identical to validated r6 path): block loads w with transposed
// assignment (thread owns wqT index j = tid+512t: f=j>>6, o=j&63, reads
// w[o*144+f]), block absmax of raw |w|, alpha = tanhf(max|w|) == max|tanhf(w)|
// (monotone tanhf, so exact), rintf half-to-even, mul-then-div like np.
// Writes wql[j] with j lane-consecutive -> conflict-free LDS writes.
//
// Sort (r5 semantics, new mechanics): u64 keys (bits<<8)|idx == exact stable
// argsort. BALLOT-RANK: key j broadcast via 2 readlanes into SGPRs (uniform
// operand only -- r7 showed per-lane readlane DATA streams serialize), then
// rank_j = sum popcll(ballot(own_key < sk)) -- popcounts on the SALU pipe.
// The rank is wave-uniform (ballot masks identical across lanes), so lane j
// keeps it via a predicated select (no writelane builtin on this toolchain).
// ZERO LDS traffic in rank (was 72 broadcast ds_read_b128/wave). Exact same
// comparison set as r2-r6.
//
// Scan: VERBATIM r5 (known-good 24.5us): LDS records (nxt-bits, wq row word
// offset) read as broadcast b128 in batches of 8; skip div/masks while
// __all(batch-last ws < 1) (exact: wq>=0 -> ws monotone); first valid spike
// == min (windows non-overlapping increasing); per-batch exits.
// fp contract OFF so cumsums round exactly like numpy (mul, then add).
// ---------------------------------------------------------------------------
__global__ __launch_bounds__(NTHR, 4) void fused_spike_kernel(
    const float* __restrict__ inp,   // (4,16,32,32)
    const float* __restrict__ w,     // (64,144)
    float* __restrict__ out)         // (4,64,32,32)
{
#pragma clang fp contract(off)
    __shared__ __align__(16) float wql[F_IN * F_OUT];          // 36 KB (144,64)
    __shared__ __align__(16) unsigned long long kr[PPB][F_IN]; // 9 KB records
    __shared__ float sv[PPB][F_IN + 1];                        // 4.5 KB sorted vals
    __shared__ float red[PPB];

    const int tid  = threadIdx.x;
    const int lane = tid & 63;
    const int wv_i = tid >> 6;                   // wave id = pixel-in-block
    const int p    = blockIdx.x * PPB + wv_i;    // pixel id
    const int b    = p >> 10;
    const int l    = p & 1023;
    const int h    = l >> 5;
    const int wc   = l & 31;

    // ---- load w (transposed assignment) + absmax ----
    float wreg[18];
    float m = 0.f;
#pragma unroll
    for (int t = 0; t < 18; ++t) {
        const int j = tid + 512 * t;    // wqT index: f = j>>6, o = j&63
        const int f = j >> 6;
        const int o = j & 63;
        const float x = w[o * F_IN + f];
        wreg[t] = x;
        m = fmaxf(m, fabsf(x));
    }
    for (int s = 32; s > 0; s >>= 1)
        m = fmaxf(m, __shfl_xor(m, s, 64));
    if (lane == 0) red[wv_i] = m;

    // ---- patch + u64 keys, registers only (f = c*9 + kh*3 + kw) ----
    float vv[3];
    unsigned long long k64[3];
    unsigned khi[3], klo[3];
#pragma unroll
    for (int mm = 0; mm < 3; ++mm) {
        const int i = lane + 64 * mm;
        float v = MAX_SPIKE;
        if (i < F_IN) {
            const int c  = i / 9;
            const int r  = i - c * 9;
            const int kh = r / 3;
            const int kw = r - kh * 3;
            const int hh = h + kh - 1;
            const int wg = wc + kw - 1;
            float x = 0.f;
            if (hh >= 0 && hh < H_IMG && wg >= 0 && wg < W_IMG)
                x = inp[((b * 16 + c) * H_IMG + hh) * W_IMG + wg];
            v = (x < 0.1f) ? MAX_SPIKE : x;
        }
        vv[mm] = v;
        k64[mm] = ((unsigned long long)__float_as_uint(v) << 8) | (unsigned)i;
        khi[mm] = (unsigned)(k64[mm] >> 32);
        klo[mm] = (unsigned)k64[mm];
    }
    if (lane == 0) sv[wv_i][F_IN] = 1.0f;        // causality sentinel

    __syncthreads();                             // red[] visible

    // ---- alpha + quantize into wql (frees wreg early) ----
    float mw = red[0];
#pragma unroll
    for (int t = 1; t < PPB; ++t) mw = fmaxf(mw, red[t]);
    const float alpha = tanhf(mw);
#pragma unroll
    for (int t = 0; t < 18; ++t) {
        const int j = tid + 512 * t;
        const float tt = tanhf(wreg[t]);
        float x = tt / alpha;                    // f32 divide (mirrors np)
        x = fminf(fmaxf(x, -1.f), 1.f) * 127.f;  // clip then *qmax
        const float r = rintf(x);                // round half-to-even
        wql[j] = r * alpha / 127.f;              // mul then div (mirrors np)
    }

    // ---- ballot rank: zero LDS; exact same u64 comparisons as r2-r6 ----
    // rank r is wave-uniform (same ballot masks everywhere); lane j keeps it.
    int vr0 = 0, vr1 = 0, vr2 = 0;
#pragma unroll 8
    for (int j = 0; j < 64; ++j) {               // keys 0..63 (m=0)
        const unsigned long long sk =
            ((unsigned long long)rl_u32(khi[0], j) << 32) | rl_u32(klo[0], j);
        const int r = (int)(__popcll(__ballot(k64[0] < sk))
                          + __popcll(__ballot(k64[1] < sk))
                          + __popcll(__ballot(k64[2] < sk) & 0xFFFFull));
        vr0 = (lane == j) ? r : vr0;
    }
#pragma unroll 8
    for (int j = 0; j < 64; ++j) {               // keys 64..127 (m=1)
        const unsigned long long sk =
            ((unsigned long long)rl_u32(khi[1], j) << 32) | rl_u32(klo[1], j);
        const int r = (int)(__popcll(__ballot(k64[0] < sk))
                          + __popcll(__ballot(k64[1] < sk))
                          + __popcll(__ballot(k64[2] < sk) & 0xFFFFull));
        vr1 = (lane == j) ? r : vr1;
    }
#pragma unroll 8
    for (int j = 0; j < 16; ++j) {               // keys 128..143 (m=2)
        const unsigned long long sk =
            ((unsigned long long)rl_u32(khi[2], j) << 32) | rl_u32(klo[2], j);
        const int r = (int)(__popcll(__ballot(k64[0] < sk))
                          + __popcll(__ballot(k64[1] < sk))
                          + __popcll(__ballot(k64[2] < sk) & 0xFFFFull));
        vr2 = (lane == j) ? r : vr2;
    }

    // ---- scatter sorted values + record-lo (wq LDS row word offset) ----
    {
        unsigned* krlo = (unsigned*)&kr[wv_i][0];   // little-endian: lo at +0
        sv[wv_i][vr0] = vv[0];  krlo[2 * vr0] = (unsigned)lane << 6;
        sv[wv_i][vr1] = vv[1];  krlo[2 * vr1] = (unsigned)(lane + 64) << 6;
        if (lane < F_IN - 128) {
            sv[wv_i][vr2] = vv[2];  krlo[2 * vr2] = (unsigned)(lane + 128) << 6;
        }
    }

    // ---- record-hi = bits of next sorted value (same-wave, in-order DS) ----
    {
        unsigned* krhi = (unsigned*)&kr[wv_i][0];
        for (int k = lane; k < F_IN; k += 64)
            krhi[2 * k + 1] = __float_as_uint(sv[wv_i][k + 1]);
    }

    // ONE block barrier: wql (written by all waves) visible before the scan.
    __syncthreads();

    // ---- batched scan (verbatim r5): first valid spike == min ----
    float s   = sv[wv_i][0];
    float ws  = 0.f;
    float iws = 0.f;
    float mn  = MAX_SPIKE;      // masked / never-valid lanes => exactly 100
    bool  done = false;
    const ulonglong2* rec2 = (const ulonglong2*)&kr[wv_i][0];
    for (int k0 = 0; k0 < F_IN; k0 += 8) {
        if (s >= MAX_SPIKE) break;            // sorted: rest contribute 100
        const ulonglong2 ra = rec2[(k0 >> 1) + 0];
        const ulonglong2 rb = rec2[(k0 >> 1) + 1];
        const ulonglong2 rc = rec2[(k0 >> 1) + 2];
        const ulonglong2 rd = rec2[(k0 >> 1) + 3];
        const unsigned long long r8[8] = { ra.x, ra.y, rb.x, rb.y,
                                           rc.x, rc.y, rd.x, rd.y };
        float su[8], nx[8], wsu[8], iwsu[8];
#pragma unroll
        for (int u = 0; u < 8; ++u) {
            su[u] = s;
            nx[u] = __uint_as_float((unsigned)(r8[u] >> 32));
            const float wvv = wql[(unsigned)r8[u] + lane];  // 2-way bank: free
            ws += wvv;
            const float prod = su[u] * wvv;   // separate rounding (no FMA)
            iws += prod;
            wsu[u]  = ws;
            iwsu[u] = iws;
            s = nx[u];
        }
        // wq >= 0 => ws monotone: if last ws of batch < 1 for all lanes, the
        // whole batch is masked (contributes exactly 100) -> skip div/compares.
        if (!__all(wsu[7] < 1.0f)) {
#pragma unroll
            for (int u = 0; u < 8; ++u) {
                const float d = fmaxf(wsu[u] - 1.0f, 1e-10f); // upper clamp never binds
                const float q = iwsu[u] / d;                  // IEEE f32 divide
                const bool valid = (wsu[u] >= 1.0f) & (q >= su[u]) & (q <= nx[u]);
                if (valid & !done) { mn = q; done = true; }
            }
            if (__all(done)) break;           // windows increase: first = min
        }
    }
    out[(b * F_OUT + lane) * 1024 + l] = mn;
}

extern "C" void kernel_launch(void* const* d_in, const int* in_sizes, int n_in,
                              void* d_out, int out_size, void* d_ws, size_t ws_size,
                              hipStream_t stream) {
    const float* inp = (const float*)d_in[0];   // 65536 elems
    const float* w   = (const float*)d_in[1];   // 9216 elems
    float* out = (float*)d_out;                 // 262144 elems

    fused_spike_kernel<<<NPIX / PPB, NTHR, 0, stream>>>(inp, w, out);
}

// Round 10
// 87.171 us; speedup vs baseline: 1.0521x; 1.0521x over previous
//
#include <hip/hip_runtime.h>
#include <math.h>

// Problem constants (fixed by reference: inp (4,16,32,32) f32, weight (64,144) f32)
constexpr int F_IN   = 144;   // 16 ch * 9 taps
constexpr int F_OUT  = 64;
constexpr int H_IMG  = 32;
constexpr int W_IMG  = 32;
constexpr int NPIX   = 4 * H_IMG * W_IMG;  // 4096
constexpr int PPB    = 8;                  // pixels per block (1 wave each)
constexpr int NTHR   = PPB * 64;           // 512
#define MAX_SPIKE 100.0f

__device__ __forceinline__ unsigned rl_u32(unsigned v, int j) {
    return (unsigned)__builtin_amdgcn_readlane((int)v, j);
}

// ---------------------------------------------------------------------------
// Weight quantization (validated r2-r6, verbatim r6):
// alpha = tanhf(max|w|) == max|tanhf(w)| (monotone, w >= 0).
// rintf = half-to-even like np.round; mul-then-div mirrors np rounding.
// COALESCED loads only -- r9 showed transposed per-thread w reads cost ~15us
// in L2 line traffic when done per-block.
// ---------------------------------------------------------------------------
__global__ __launch_bounds__(256) void quant_fused_kernel(
    const float* __restrict__ w,
    float* __restrict__ wqT)   // (144,64) transposed
{
#pragma clang fp contract(off)
    __shared__ float wred[4];
    const int tid = threadIdx.x;

    float m = 0.f;
    {
        const float4* w4 = (const float4*)w;
        for (int i = tid; i < (F_OUT * F_IN) / 4; i += 256) {
            const float4 v = w4[i];
            m = fmaxf(m, fmaxf(fmaxf(fabsf(v.x), fabsf(v.y)),
                               fmaxf(fabsf(v.z), fabsf(v.w))));
        }
    }
    for (int s = 32; s > 0; s >>= 1)
        m = fmaxf(m, __shfl_xor(m, s, 64));
    if ((tid & 63) == 0) wred[tid >> 6] = m;
    __syncthreads();
    const float mw = fmaxf(fmaxf(wred[0], wred[1]), fmaxf(wred[2], wred[3]));
    const float alpha = tanhf(mw);

    const int i = blockIdx.x * 256 + tid;   // 36*256 = 9216 exactly
    const int o = i / F_IN;
    const int f = i - o * F_IN;
    const float t = tanhf(w[i]);
    float x = t / alpha;                       // f32 divide (mirrors np)
    x = fminf(fmaxf(x, -1.f), 1.f) * 127.f;    // clip then *qmax
    const float r = rintf(x);                  // round half-to-even
    wqT[f * F_OUT + o] = r * alpha / 127.f;    // mul then div (mirrors np)
}

// ---------------------------------------------------------------------------
// Spike conv v7 = r6's v5 structure with BALLOT-RANK (the one new variable):
//   - u64 keys (bits<<8)|idx stay in REGISTERS (3/lane); rank of pivot j =
//     sum popcll(ballot(own_key < pivot)) -- pivot broadcast via 2 readlanes
//     into SGPRs (uniform operand only; r7 showed per-lane readlane DATA
//     streams serialize), comparisons are lane-parallel v_cmp_lt_u64, counts
//     on the SALU pipe; rank is wave-uniform so lane j keeps it via
//     predicated select. ZERO LDS traffic in rank (was 72 broadcast
//     ds_read_b128/wave = the LDS-pipe serializer). Exact same u64
//     comparison set as r2-r6 -> bit-identical permutation.
//   - everything else verbatim r6: async global_load_lds wq staging, records
//     scatter + b128 broadcast scan, batch-8 scan with exact early exits,
//     ONE block barrier.
// fp contract OFF so cumsums round exactly like numpy (mul, then add).
// ---------------------------------------------------------------------------
__global__ __launch_bounds__(NTHR, 4) void spike_conv_kernel(
    const float* __restrict__ inp,   // (4,16,32,32)
    const float* __restrict__ wq,    // (144,64)
    float* __restrict__ out)         // (4,64,32,32)
{
#pragma clang fp contract(off)
    __shared__ __align__(16) float wql[F_IN * F_OUT];          // 36 KB
    __shared__ __align__(16) unsigned long long kr[PPB][F_IN]; // 9 KB records
    __shared__ float sv[PPB][F_IN + 1];                        // 4.5 KB

    const int tid  = threadIdx.x;
    const int lane = tid & 63;
    const int wv_i = tid >> 6;                   // wave id = pixel-in-block
    const int p    = blockIdx.x * PPB + wv_i;    // pixel id
    const int b    = p >> 10;
    const int l    = p & 1023;
    const int h    = l >> 5;
    const int wc   = l & 31;

    // ---- async stage wq -> LDS: 36 chunks of 1 KB (64 lanes x 16 B) ----
    for (int c = wv_i; c < 36; c += PPB) {
        const float* g = wq + c * 256 + lane * 4;
        __builtin_amdgcn_global_load_lds(
            (const __attribute__((address_space(1))) void*)g,
            (__attribute__((address_space(3))) void*)&wql[c * 256],
            16, 0, 0);
    }

    // ---- patch + u64 keys, registers only (f = c*9 + kh*3 + kw) ----
    float vv[3];
    unsigned long long k64[3];
    unsigned khi[3], klo[3];
#pragma unroll
    for (int mm = 0; mm < 3; ++mm) {
        const int i = lane + 64 * mm;
        float v = MAX_SPIKE;
        if (i < F_IN) {
            const int c  = i / 9;
            const int r  = i - c * 9;
            const int kh = r / 3;
            const int kw = r - kh * 3;
            const int hh = h + kh - 1;
            const int wg = wc + kw - 1;
            float x = 0.f;
            if (hh >= 0 && hh < H_IMG && wg >= 0 && wg < W_IMG)
                x = inp[((b * 16 + c) * H_IMG + hh) * W_IMG + wg];
            v = (x < 0.1f) ? MAX_SPIKE : x;
        }
        vv[mm] = v;
        k64[mm] = ((unsigned long long)__float_as_uint(v) << 8) | (unsigned)i;
        khi[mm] = (unsigned)(k64[mm] >> 32);
        klo[mm] = (unsigned)k64[mm];
    }
    if (lane == 0) sv[wv_i][F_IN] = 1.0f;        // causality sentinel

    // ---- ballot rank: zero LDS; exact same u64 comparisons as r2-r6 ----
    int vr0 = 0, vr1 = 0, vr2 = 0;
#pragma unroll 8
    for (int j = 0; j < 64; ++j) {               // keys 0..63 (m=0)
        const unsigned long long sk =
            ((unsigned long long)rl_u32(khi[0], j) << 32) | rl_u32(klo[0], j);
        const int r = (int)(__popcll(__ballot(k64[0] < sk))
                          + __popcll(__ballot(k64[1] < sk))
                          + __popcll(__ballot(k64[2] < sk) & 0xFFFFull));
        vr0 = (lane == j) ? r : vr0;
    }
#pragma unroll 8
    for (int j = 0; j < 64; ++j) {               // keys 64..127 (m=1)
        const unsigned long long sk =
            ((unsigned long long)rl_u32(khi[1], j) << 32) | rl_u32(klo[1], j);
        const int r = (int)(__popcll(__ballot(k64[0] < sk))
                          + __popcll(__ballot(k64[1] < sk))
                          + __popcll(__ballot(k64[2] < sk) & 0xFFFFull));
        vr1 = (lane == j) ? r : vr1;
    }
#pragma unroll 8
    for (int j = 0; j < 16; ++j) {               // keys 128..143 (m=2)
        const unsigned long long sk =
            ((unsigned long long)rl_u32(khi[2], j) << 32) | rl_u32(klo[2], j);
        const int r = (int)(__popcll(__ballot(k64[0] < sk))
                          + __popcll(__ballot(k64[1] < sk))
                          + __popcll(__ballot(k64[2] < sk) & 0xFFFFull));
        vr2 = (lane == j) ? r : vr2;
    }

    // ---- scatter sorted values + record-lo (wq LDS row word offset) ----
    {
        unsigned* krlo = (unsigned*)&kr[wv_i][0];   // little-endian: lo at +0
        sv[wv_i][vr0] = vv[0];  krlo[2 * vr0] = (unsigned)lane << 6;
        sv[wv_i][vr1] = vv[1];  krlo[2 * vr1] = (unsigned)(lane + 64) << 6;
        if (lane < F_IN - 128) {
            sv[wv_i][vr2] = vv[2];  krlo[2 * vr2] = (unsigned)(lane + 128) << 6;
        }
    }

    // ---- record-hi = bits of next sorted value (same-wave, in-order DS) ----
    {
        unsigned* krhi = (unsigned*)&kr[wv_i][0];
        for (int k = lane; k < F_IN; k += 64)
            krhi[2 * k + 1] = __float_as_uint(sv[wv_i][k + 1]);
    }

    // ONE block barrier: wql visible to all waves + async vmcnt drained.
    __syncthreads();

    // ---- batched scan (verbatim r5/r6): first valid spike == min ----
    float s   = sv[wv_i][0];
    float ws  = 0.f;
    float iws = 0.f;
    float mn  = MAX_SPIKE;      // masked / never-valid lanes => exactly 100
    bool  done = false;
    const ulonglong2* rec2 = (const ulonglong2*)&kr[wv_i][0];
    for (int k0 = 0; k0 < F_IN; k0 += 8) {
        if (s >= MAX_SPIKE) break;            // sorted: rest contribute 100
        const ulonglong2 ra = rec2[(k0 >> 1) + 0];
        const ulonglong2 rb = rec2[(k0 >> 1) + 1];
        const ulonglong2 rc = rec2[(k0 >> 1) + 2];
        const ulonglong2 rd = rec2[(k0 >> 1) + 3];
        const unsigned long long r8[8] = { ra.x, ra.y, rb.x, rb.y,
                                           rc.x, rc.y, rd.x, rd.y };
        float su[8], nx[8], wsu[8], iwsu[8];
#pragma unroll
        for (int u = 0; u < 8; ++u) {
            su[u] = s;
            nx[u] = __uint_as_float((unsigned)(r8[u] >> 32));
            const float wvv = wql[(unsigned)r8[u] + lane];  // 2-way bank: free
            ws += wvv;
            const float prod = su[u] * wvv;   // separate rounding (no FMA)
            iws += prod;
            wsu[u]  = ws;
            iwsu[u] = iws;
            s = nx[u];
        }
        // wq >= 0 => ws monotone: if last ws of batch < 1 for all lanes, the
        // whole batch is masked (contributes exactly 100) -> skip div/compares.
        if (!__all(wsu[7] < 1.0f)) {
#pragma unroll
            for (int u = 0; u < 8; ++u) {
                const float d = fmaxf(wsu[u] - 1.0f, 1e-10f); // upper clamp never binds
                const float q = iwsu[u] / d;                  // IEEE f32 divide
                const bool valid = (wsu[u] >= 1.0f) & (q >= su[u]) & (q <= nx[u]);
                if (valid & !done) { mn = q; done = true; }
            }
            if (__all(done)) break;           // windows increase: first = min
        }
    }
    out[(b * F_OUT + lane) * 1024 + l] = mn;
}

extern "C" void kernel_launch(void* const* d_in, const int* in_sizes, int n_in,
                              void* d_out, int out_size, void* d_ws, size_t ws_size,
                              hipStream_t stream) {
    const float* inp = (const float*)d_in[0];   // 65536 elems
    const float* w   = (const float*)d_in[1];   // 9216 elems
    float* out = (float*)d_out;                 // 262144 elems
    float* wqT = (float*)d_ws;                  // 9216 floats scratch

    quant_fused_kernel<<<36, 256, 0, stream>>>(w, wqT);
    spike_conv_kernel<<<NPIX / PPB, NTHR, 0, stream>>>(inp, wqT, out);
}

// Round 11
// 81.552 us; speedup vs baseline: 1.1245x; 1.0689x over previous
//
#include <hip/hip_runtime.h>
#include <math.h>

// Problem constants (fixed by reference: inp (4,16,32,32) f32, weight (64,144) f32)
constexpr int F_IN   = 144;   // 16 ch * 9 taps
constexpr int F_OUT  = 64;
constexpr int H_IMG  = 32;
constexpr int W_IMG  = 32;
constexpr int NPIX   = 4 * H_IMG * W_IMG;  // 4096
constexpr int PPB    = 8;                  // pixels per block (1 wave each)
constexpr int NTHR   = PPB * 64;           // 512
#define MAX_SPIKE 100.0f

// ---------------------------------------------------------------------------
// Weight quantization (validated r2-r6, verbatim r6):
// alpha = tanhf(max|w|) == max|tanhf(w)| (monotone, w >= 0).
// rintf = half-to-even like np.round; mul-then-div mirrors np rounding.
// ---------------------------------------------------------------------------
__global__ __launch_bounds__(256) void quant_fused_kernel(
    const float* __restrict__ w,
    float* __restrict__ wqT)   // (144,64) transposed
{
#pragma clang fp contract(off)
    __shared__ float wred[4];
    const int tid = threadIdx.x;

    float m = 0.f;
    {
        const float4* w4 = (const float4*)w;
        for (int i = tid; i < (F_OUT * F_IN) / 4; i += 256) {
            const float4 v = w4[i];
            m = fmaxf(m, fmaxf(fmaxf(fabsf(v.x), fabsf(v.y)),
                               fmaxf(fabsf(v.z), fabsf(v.w))));
        }
    }
    for (int s = 32; s > 0; s >>= 1)
        m = fmaxf(m, __shfl_xor(m, s, 64));
    if ((tid & 63) == 0) wred[tid >> 6] = m;
    __syncthreads();
    const float mw = fmaxf(fmaxf(wred[0], wred[1]), fmaxf(wred[2], wred[3]));
    const float alpha = tanhf(mw);

    const int i = blockIdx.x * 256 + tid;   // 36*256 = 9216 exactly
    const int o = i / F_IN;
    const int f = i - o * F_IN;
    const float t = tanhf(w[i]);
    float x = t / alpha;                       // f32 divide (mirrors np)
    x = fminf(fmaxf(x, -1.f), 1.f) * 127.f;    // clip then *qmax
    const float r = rintf(x);                  // round half-to-even
    wqT[f * F_OUT + o] = r * alpha / 127.f;    // mul then div (mirrors np)
}

// ---------------------------------------------------------------------------
// Spike conv v8 = r6's v5 (best measured) with a SOFTWARE-PIPELINED scan:
//   - records for batch k+1 prefetched (branchless clamped index) during
//     batch k -> the ds_read_b128 latency no longer sits on the serial
//     k-chain (which was: records -> s=nx[7] -> branch -> next records)
//   - the `s >= 100` break is REMOVED: it saved ~2 batches (only ~10% of
//     inputs are masked, so s reaches 100 near k~130) but serialized every
//     batch on nx[7]. Processing those slots is exactly what the reference
//     does: they produce spike == 100 == mn-init, so output is unchanged.
//   - rank sort, staging, scatter: verbatim r6 (r7/r10 proved readlane and
//     ballot rank variants both LOSE to LDS b128 broadcast).
// Exact math per slot unchanged (validated r2-r6): sequential cumsums with
// separate mul+add rounding, IEEE f32 divide, reference mask order,
// first-valid==min (windows non-overlapping increasing), masked-batch skip
// (exact: wq >= 0 -> ws monotone).
// fp contract OFF so cumsums round exactly like numpy (mul, then add).
// ---------------------------------------------------------------------------
__global__ __launch_bounds__(NTHR, 4) void spike_conv_kernel(
    const float* __restrict__ inp,   // (4,16,32,32)
    const float* __restrict__ wq,    // (144,64)
    float* __restrict__ out)         // (4,64,32,32)
{
#pragma clang fp contract(off)
    __shared__ __align__(16) float wql[F_IN * F_OUT];          // 36 KB
    __shared__ __align__(16) unsigned long long kr[PPB][F_IN]; // 9 KB records
    __shared__ float sv[PPB][F_IN + 1];                        // 4.5 KB

    const int tid  = threadIdx.x;
    const int lane = tid & 63;
    const int wv_i = tid >> 6;                   // wave id = pixel-in-block
    const int p    = blockIdx.x * PPB + wv_i;    // pixel id
    const int b    = p >> 10;
    const int l    = p & 1023;
    const int h    = l >> 5;
    const int wc   = l & 31;

    // ---- async stage wq -> LDS: 36 chunks of 1 KB (64 lanes x 16 B) ----
    for (int c = wv_i; c < 36; c += PPB) {
        const float* g = wq + c * 256 + lane * 4;
        __builtin_amdgcn_global_load_lds(
            (const __attribute__((address_space(1))) void*)g,
            (__attribute__((address_space(3))) void*)&wql[c * 256],
            16, 0, 0);
    }

    // ---- stage patch, build keys into LDS (feature f = c*9 + kh*3 + kw) ----
    float v0f, v1f, v2f;
    unsigned long long key0, key1, key2;
    {
        int idx[3] = { lane, lane + 64, lane + 128 };
        float vals[3];
        for (int m = 0; m < 3; ++m) {
            const int i = idx[m];
            float v = MAX_SPIKE;
            if (i < F_IN) {
                const int c  = i / 9;
                const int r  = i - c * 9;
                const int kh = r / 3;
                const int kw = r - kh * 3;
                const int hh = h + kh - 1;
                const int wg = wc + kw - 1;
                float x = 0.f;
                if (hh >= 0 && hh < H_IMG && wg >= 0 && wg < W_IMG)
                    x = inp[((b * 16 + c) * H_IMG + hh) * W_IMG + wg];
                v = (x < 0.1f) ? MAX_SPIKE : x;
                kr[wv_i][i] = ((unsigned long long)__float_as_uint(v) << 8)
                              | (unsigned)i;
            }
            vals[m] = v;
        }
        v0f = vals[0]; v1f = vals[1]; v2f = vals[2];
        key0 = ((unsigned long long)__float_as_uint(v0f) << 8) | (unsigned)idx[0];
        key1 = ((unsigned long long)__float_as_uint(v1f) << 8) | (unsigned)idx[1];
        key2 = ((unsigned long long)__float_as_uint(v2f) << 8) | (unsigned)idx[2];
        if (lane == 0) sv[wv_i][F_IN] = 1.0f;    // causality sentinel
    }
    // kr/sv wave-private: same-wave DS ordering is in-order -> no barrier.

    // ---- rank sort (keys unique -> strict < == exact stable permutation) ----
    int r0 = 0, r1 = 0, r2 = 0;
    {
        const ulonglong2* ks2 = (const ulonglong2*)&kr[wv_i][0];
#pragma unroll 4
        for (int j = 0; j < F_IN / 2; ++j) {
            const ulonglong2 kk = ks2[j];   // wave-broadcast read: conflict-free
            r0 += (kk.x < key0) + (kk.y < key0);
            r1 += (kk.x < key1) + (kk.y < key1);
            r2 += (kk.x < key2) + (kk.y < key2);
        }
    }

    // ---- scatter sorted values + record-lo (wq LDS row word offset) ----
    {
        unsigned* krlo = (unsigned*)&kr[wv_i][0];   // little-endian: lo at +0
        sv[wv_i][r0] = v0f;  krlo[2 * r0] = (unsigned)lane << 6;
        sv[wv_i][r1] = v1f;  krlo[2 * r1] = (unsigned)(lane + 64) << 6;
        if (lane < F_IN - 128) {
            sv[wv_i][r2] = v2f;  krlo[2 * r2] = (unsigned)(lane + 128) << 6;
        }
    }

    // ---- record-hi = bits of next sorted value (same-wave, in-order DS) ----
    {
        unsigned* krhi = (unsigned*)&kr[wv_i][0];
        for (int k = lane; k < F_IN; k += 64)
            krhi[2 * k + 1] = __float_as_uint(sv[wv_i][k + 1]);
    }

    // ONE block barrier: wql visible to all waves + async vmcnt drained.
    __syncthreads();

    // ---- pipelined batched scan: first valid spike == min ----
    float s   = sv[wv_i][0];
    float ws  = 0.f;
    float iws = 0.f;
    float mn  = MAX_SPIKE;      // masked / never-valid lanes => exactly 100
    bool  done = false;
    const ulonglong2* rec2 = (const ulonglong2*)&kr[wv_i][0];
    ulonglong2 ra = rec2[0], rb = rec2[1], rc = rec2[2], rd = rec2[3];
    for (int k0 = 0; k0 < F_IN; k0 += 8) {
        // prefetch next batch's records (branchless: clamp to last valid base)
        const int nidx = ((k0 >> 1) + 4 <= 68) ? (k0 >> 1) + 4 : 68;
        const ulonglong2 na = rec2[nidx + 0];
        const ulonglong2 nb = rec2[nidx + 1];
        const ulonglong2 nc = rec2[nidx + 2];
        const ulonglong2 nd = rec2[nidx + 3];

        const unsigned long long r8[8] = { ra.x, ra.y, rb.x, rb.y,
                                           rc.x, rc.y, rd.x, rd.y };
        float su[8], nx[8], wsu[8], iwsu[8];
#pragma unroll
        for (int u = 0; u < 8; ++u) {
            su[u] = s;
            nx[u] = __uint_as_float((unsigned)(r8[u] >> 32));
            const float wvv = wql[(unsigned)r8[u] + lane];  // 2-way bank: free
            ws += wvv;
            const float prod = su[u] * wvv;   // separate rounding (no FMA)
            iws += prod;
            wsu[u]  = ws;
            iwsu[u] = iws;
            s = nx[u];
        }
        // wq >= 0 => ws monotone: if last ws of batch < 1 for all lanes, the
        // whole batch is masked (contributes exactly 100) -> skip div/compares.
        if (!__all(wsu[7] < 1.0f)) {
#pragma unroll
            for (int u = 0; u < 8; ++u) {
                const float d = fmaxf(wsu[u] - 1.0f, 1e-10f); // upper clamp never binds
                const float q = iwsu[u] / d;                  // IEEE f32 divide
                const bool valid = (wsu[u] >= 1.0f) & (q >= su[u]) & (q <= nx[u]);
                if (valid & !done) { mn = q; done = true; }
            }
            if (__all(done)) break;           // windows increase: first = min
        }
        ra = na; rb = nb; rc = nc; rd = nd;
    }
    out[(b * F_OUT + lane) * 1024 + l] = mn;
}

extern "C" void kernel_launch(void* const* d_in, const int* in_sizes, int n_in,
                              void* d_out, int out_size, void* d_ws, size_t ws_size,
                              hipStream_t stream) {
    const float* inp = (const float*)d_in[0];   // 65536 elems
    const float* w   = (const float*)d_in[1];   // 9216 elems
    float* out = (float*)d_out;                 // 262144 elems
    float* wqT = (float*)d_ws;                  // 9216 floats scratch

    quant_fused_kernel<<<36, 256, 0, stream>>>(w, wqT);
    spike_conv_kernel<<<NPIX / PPB, NTHR, 0, stream>>>(inp, wqT, out);
}